// Round 1
// baseline (245.919 us; speedup 1.0000x reference)
//
#include <hip/hip_runtime.h>
#include <hip/hip_bf16.h>
#include <math.h>

#define T_DIM 2048
#define B_DIM 2
#define E_DIM 1024
#define H_DIM 16
#define HD_DIM 64
#define M_DIM (T_DIM * B_DIM)   // 4096 rows (t*B+b)
#define BH_DIM (B_DIM * H_DIM)  // 32 head-batches

using bf16x8 = __attribute__((ext_vector_type(8))) __bf16;
using f32x4  = __attribute__((ext_vector_type(4))) float;
using u32x4  = __attribute__((ext_vector_type(4))) unsigned int;

static __device__ __forceinline__ unsigned short f2bf(float f) {
  unsigned u = __builtin_bit_cast(unsigned, f);
  u += 0x7fff + ((u >> 16) & 1);   // RNE
  return (unsigned short)(u >> 16);
}

__device__ __forceinline__ void gload_lds16(const void* g, void* l) {
  __builtin_amdgcn_global_load_lds(
      (const __attribute__((address_space(1))) unsigned int*)g,
      (__attribute__((address_space(3))) unsigned int*)l, 16, 0, 0);
}

// ---------------- fp32 -> bf16 cast (weights) ----------------
__global__ __launch_bounds__(256) void cast_bf16_kernel(
    const float* __restrict__ in, unsigned short* __restrict__ out, int n4) {
  int i = blockIdx.x * 256 + threadIdx.x;
  if (i >= n4) return;
  float4 v = ((const float4*)in)[i];
  ushort4 o;
  o.x = f2bf(v.x); o.y = f2bf(v.y); o.z = f2bf(v.z); o.w = f2bf(v.w);
  ((ushort4*)out)[i] = o;
}

// ---------------- LayerNorm (row = one block) ----------------
__global__ __launch_bounds__(256) void ln_kernel(
    const float* __restrict__ q, const float* __restrict__ gamma,
    const float* __restrict__ beta, unsigned short* __restrict__ out) {
  int row = blockIdx.x;
  int tid = threadIdx.x;
  const float4* qr = (const float4*)(q + (size_t)row * E_DIM);
  float4 x = qr[tid];
  float s  = x.x + x.y + x.z + x.w;
  float ss = x.x * x.x + x.y * x.y + x.z * x.z + x.w * x.w;
#pragma unroll
  for (int off = 32; off >= 1; off >>= 1) {
    s  += __shfl_xor(s, off, 64);
    ss += __shfl_xor(ss, off, 64);
  }
  __shared__ float red[8];
  int wid = tid >> 6, lane = tid & 63;
  if (lane == 0) { red[wid] = s; red[4 + wid] = ss; }
  __syncthreads();
  s  = red[0] + red[1] + red[2] + red[3];
  ss = red[4] + red[5] + red[6] + red[7];
  float mean = s * (1.0f / E_DIM);
  float var  = ss * (1.0f / E_DIM) - mean * mean;
  float rstd = rsqrtf(var + 1e-5f);
  float4 g4 = ((const float4*)gamma)[tid];
  float4 b4 = ((const float4*)beta)[tid];
  ushort4 o;
  o.x = f2bf((x.x - mean) * rstd * g4.x + b4.x);
  o.y = f2bf((x.y - mean) * rstd * g4.y + b4.y);
  o.z = f2bf((x.z - mean) * rstd * g4.z + b4.z);
  o.w = f2bf((x.w - mean) * rstd * g4.w + b4.w);
  ((ushort4*)(out + (size_t)row * E_DIM))[tid] = o;
}

// ---------------- GEMM: C[M,N] = A[M,K] * Bw[N,K]^T (bf16 in, fp32 acc) ----
// MODE 0: scatter to qkv buffers [3][BH][T][64] as bf16
// MODE 1: out_f = resid + C (fp32)
template <int MODE>
__global__ __launch_bounds__(256) void gemm_bt_kernel(
    const unsigned short* __restrict__ A, const unsigned short* __restrict__ Bw,
    const float* __restrict__ resid, unsigned short* __restrict__ out_qkv,
    float* __restrict__ out_f, int Kv, int Nv) {
  __shared__ alignas(16) unsigned short lA[128 * 32];
  __shared__ alignas(16) unsigned short lB[128 * 32];
  int tid = threadIdx.x;
  int wid = tid >> 6, lane = tid & 63;
  int wm = wid >> 1, wn = wid & 1;
  int g = lane >> 4, lr = lane & 15;
  int m0 = blockIdx.y * 128, n0 = blockIdx.x * 128;
  f32x4 acc[4][4] = {};

  for (int k0 = 0; k0 < Kv; k0 += 32) {
#pragma unroll
    for (int c = 0; c < 2; ++c) {
      int f16 = c * 256 + tid;
      int row = f16 >> 2, col8 = (f16 & 3) << 3;
      gload_lds16(A  + (size_t)(m0 + row) * Kv + k0 + col8,
                  lA + (size_t)(c * 256 + wid * 64) * 8);
      gload_lds16(Bw + (size_t)(n0 + row) * Kv + k0 + col8,
                  lB + (size_t)(c * 256 + wid * 64) * 8);
    }
    __syncthreads();
    bf16x8 af[4], bfr[4];
#pragma unroll
    for (int r = 0; r < 4; ++r) {
      af[r]  = *(const bf16x8*)(lA + (wm * 64 + r * 16 + lr) * 32 + g * 8);
      bfr[r] = *(const bf16x8*)(lB + (wn * 64 + r * 16 + lr) * 32 + g * 8);
    }
#pragma unroll
    for (int mr = 0; mr < 4; ++mr)
#pragma unroll
      for (int nr = 0; nr < 4; ++nr)
        acc[mr][nr] = __builtin_amdgcn_mfma_f32_16x16x32_bf16(
            af[mr], bfr[nr], acc[mr][nr], 0, 0, 0);
    __syncthreads();
  }

#pragma unroll
  for (int mr = 0; mr < 4; ++mr) {
#pragma unroll
    for (int nr = 0; nr < 4; ++nr) {
#pragma unroll
      for (int r = 0; r < 4; ++r) {
        int grow = m0 + wm * 64 + mr * 16 + g * 4 + r;
        int gcol = n0 + wn * 64 + nr * 16 + lr;
        float v = acc[mr][nr][r];
        if (MODE == 0) {
          int which = gcol >> 10, rem = gcol & 1023;
          int h = rem >> 6, d = rem & 63;
          int t = grow >> 1, b = grow & 1;
          out_qkv[(size_t)which * (BH_DIM * T_DIM * HD_DIM) +
                  ((size_t)(b * H_DIM + h) * T_DIM + t) * HD_DIM + d] = f2bf(v);
        } else {
          size_t idx = (size_t)grow * Nv + gcol;
          out_f[idx] = resid[idx] + v;
        }
      }
    }
  }
}

// ---------------- Flash attention: one (b,h), 64 q-rows per block ---------
__global__ __launch_bounds__(256) void attn_kernel(
    const unsigned short* __restrict__ qb, const unsigned short* __restrict__ kb,
    const unsigned short* __restrict__ vb, unsigned short* __restrict__ ctx) {
  __shared__ alignas(16) unsigned short lK[64 * 72];       // K [k][d] pad 72
  __shared__ alignas(16) unsigned short lV[64 * 72];       // V^T [d][k] pad 72
  __shared__ alignas(16) unsigned short lP[4][16 * 72];    // per-wave P [q][k]
  int tid = threadIdx.x;
  int wid = tid >> 6, lane = tid & 63;
  int g = lane >> 4, lr = lane & 15;
  int bh = blockIdx.y;
  int b = bh >> 4, h = bh & 15;
  int qt = blockIdx.x;
  const size_t headoff = (size_t)bh * T_DIM * HD_DIM;

  int qrow = qt * 64 + wid * 16 + lr;
  bf16x8 qf[2];
#pragma unroll
  for (int ks = 0; ks < 2; ++ks)
    qf[ks] = *(const bf16x8*)(qb + headoff + (size_t)qrow * 64 + ks * 32 + g * 8);

  f32x4 accO[4] = {};
  float mrun[4], lrun[4];
#pragma unroll
  for (int r = 0; r < 4; ++r) { mrun[r] = -1e30f; lrun[r] = 0.0f; }

  for (int s0 = 0; s0 < T_DIM; s0 += 64) {
    // stage K (padded, reg-staged) and V^T
#pragma unroll
    for (int e = 0; e < 2; ++e) {
      int idx8 = e * 256 + tid;
      int kr = idx8 >> 3, d0 = (idx8 & 7) << 3;
      bf16x8 kv = *(const bf16x8*)(kb + headoff + (size_t)(s0 + kr) * 64 + d0);
      *(bf16x8*)(lK + kr * 72 + d0) = kv;
      u32x4 vv = *(const u32x4*)(vb + headoff + (size_t)(s0 + kr) * 64 + d0);
#pragma unroll
      for (int jw = 0; jw < 4; ++jw) {
        unsigned w = vv[jw];
        lV[(d0 + 2 * jw + 0) * 72 + kr] = (unsigned short)(w & 0xffff);
        lV[(d0 + 2 * jw + 1) * 72 + kr] = (unsigned short)(w >> 16);
      }
    }
    __syncthreads();

    // S = Q K^T * scale   (per lane: sc[cf][r], q-row g*4+r, key cf*16+lr)
    float sc[4][4];
#pragma unroll
    for (int cf = 0; cf < 4; ++cf) {
      bf16x8 k0f = *(const bf16x8*)(lK + (cf * 16 + lr) * 72 + 0  + g * 8);
      bf16x8 k1f = *(const bf16x8*)(lK + (cf * 16 + lr) * 72 + 32 + g * 8);
      f32x4 s = {};
      s = __builtin_amdgcn_mfma_f32_16x16x32_bf16(qf[0], k0f, s, 0, 0, 0);
      s = __builtin_amdgcn_mfma_f32_16x16x32_bf16(qf[1], k1f, s, 0, 0, 0);
#pragma unroll
      for (int r = 0; r < 4; ++r) sc[cf][r] = s[r] * 0.125f;
    }

    // online softmax, wave-parallel across the 16-lane key groups
#pragma unroll
    for (int r = 0; r < 4; ++r) {
      float mnew = fmaxf(fmaxf(sc[0][r], sc[1][r]), fmaxf(sc[2][r], sc[3][r]));
#pragma unroll
      for (int off = 8; off >= 1; off >>= 1)
        mnew = fmaxf(mnew, __shfl_xor(mnew, off, 64));
      float mtot  = fmaxf(mrun[r], mnew);
      float alpha = __expf(mrun[r] - mtot);
      float rs = 0.0f;
#pragma unroll
      for (int cf = 0; cf < 4; ++cf) {
        float p = __expf(sc[cf][r] - mtot);
        sc[cf][r] = p;
        rs += p;
      }
#pragma unroll
      for (int off = 8; off >= 1; off >>= 1)
        rs += __shfl_xor(rs, off, 64);
      lrun[r] = lrun[r] * alpha + rs;
      mrun[r] = mtot;
#pragma unroll
      for (int df = 0; df < 4; ++df) accO[df][r] *= alpha;
#pragma unroll
      for (int cf = 0; cf < 4; ++cf)
        lP[wid][(g * 4 + r) * 72 + cf * 16 + lr] = f2bf(sc[cf][r]);
    }

    // O += P V
#pragma unroll
    for (int ks = 0; ks < 2; ++ks) {
      bf16x8 pf = *(const bf16x8*)(&lP[wid][lr * 72 + ks * 32 + g * 8]);
#pragma unroll
      for (int df = 0; df < 4; ++df) {
        bf16x8 vf = *(const bf16x8*)(lV + (df * 16 + lr) * 72 + ks * 32 + g * 8);
        accO[df] = __builtin_amdgcn_mfma_f32_16x16x32_bf16(pf, vf, accO[df], 0, 0, 0);
      }
    }
    __syncthreads();
  }

  // ctx[t*B+b][h*64+d] bf16
#pragma unroll
  for (int df = 0; df < 4; ++df) {
#pragma unroll
    for (int r = 0; r < 4; ++r) {
      int t = qt * 64 + wid * 16 + g * 4 + r;
      int col = h * HD_DIM + df * 16 + lr;
      float o = accO[df][r] / lrun[r];
      ctx[((size_t)t * B_DIM + b) * E_DIM + col] = f2bf(o);
    }
  }
}

// ---------------- launcher ----------------
extern "C" void kernel_launch(void* const* d_in, const int* in_sizes, int n_in,
                              void* d_out, int out_size, void* d_ws, size_t ws_size,
                              hipStream_t stream) {
  const float* query = (const float*)d_in[0];
  const float* gamma = (const float*)d_in[1];
  const float* beta  = (const float*)d_in[2];
  const float* w_in  = (const float*)d_in[3];
  const float* w_out = (const float*)d_in[4];
  float* out = (float*)d_out;

  unsigned short* ws    = (unsigned short*)d_ws;
  unsigned short* ln    = ws;                                         // 4096*1024
  unsigned short* winb  = ln + (size_t)M_DIM * E_DIM;                 // 3072*1024
  unsigned short* woutb = winb + (size_t)3 * E_DIM * E_DIM;           // 1024*1024
  unsigned short* qkv   = woutb + (size_t)E_DIM * E_DIM;              // 3*32*2048*64
  unsigned short* ctx   = ln;  // reuse ln buffer (done before attn writes)

  unsigned short* qbuf = qkv;
  unsigned short* kbuf = qkv + (size_t)BH_DIM * T_DIM * HD_DIM;
  unsigned short* vbuf = kbuf + (size_t)BH_DIM * T_DIM * HD_DIM;

  cast_bf16_kernel<<<dim3(3072), dim3(256), 0, stream>>>(w_in, winb, 3 * E_DIM * E_DIM / 4);
  cast_bf16_kernel<<<dim3(1024), dim3(256), 0, stream>>>(w_out, woutb, E_DIM * E_DIM / 4);
  ln_kernel<<<dim3(M_DIM), dim3(256), 0, stream>>>(query, gamma, beta, ln);
  gemm_bt_kernel<0><<<dim3(3 * E_DIM / 128, M_DIM / 128), dim3(256), 0, stream>>>(
      ln, winb, nullptr, qkv, nullptr, E_DIM, 3 * E_DIM);
  attn_kernel<<<dim3(T_DIM / 64, BH_DIM), dim3(256), 0, stream>>>(qbuf, kbuf, vbuf, ctx);
  gemm_bt_kernel<1><<<dim3(E_DIM / 128, M_DIM / 128), dim3(256), 0, stream>>>(
      ctx, woutb, query, nullptr, out, E_DIM, E_DIM);
}

// Round 3
// 218.858 us; speedup vs baseline: 1.1236x; 1.1236x over previous
//
#include <hip/hip_runtime.h>
#include <hip/hip_bf16.h>
#include <math.h>

#define T_DIM 2048
#define B_DIM 2
#define E_DIM 1024
#define H_DIM 16
#define HD_DIM 64
#define M_DIM (T_DIM * B_DIM)   // 4096 rows (t*B+b)
#define BH_DIM (B_DIM * H_DIM)  // 32 head-batches

using bf16x8 = __attribute__((ext_vector_type(8))) __bf16;
using u16x8  = __attribute__((ext_vector_type(8))) unsigned short;
using f32x4  = __attribute__((ext_vector_type(4))) float;

static __device__ __forceinline__ unsigned short f2bf(float f) {
  unsigned u = __builtin_bit_cast(unsigned, f);
  u += 0x7fff + ((u >> 16) & 1);   // RNE
  return (unsigned short)(u >> 16);
}

__device__ __forceinline__ void gload_lds16(const void* g, void* l) {
  __builtin_amdgcn_global_load_lds(
      (const __attribute__((address_space(1))) unsigned int*)g,
      (__attribute__((address_space(3))) unsigned int*)l, 16, 0, 0);
}

// ---------------- fp32 -> bf16 cast (weights) ----------------
__global__ __launch_bounds__(256) void cast_bf16_kernel(
    const float* __restrict__ in, unsigned short* __restrict__ out, int n4) {
  int i = blockIdx.x * 256 + threadIdx.x;
  if (i >= n4) return;
  float4 v = ((const float4*)in)[i];
  ushort4 o;
  o.x = f2bf(v.x); o.y = f2bf(v.y); o.z = f2bf(v.z); o.w = f2bf(v.w);
  ((ushort4*)out)[i] = o;
}

// ---------------- LayerNorm (row = one block) ----------------
__global__ __launch_bounds__(256) void ln_kernel(
    const float* __restrict__ q, const float* __restrict__ gamma,
    const float* __restrict__ beta, unsigned short* __restrict__ out) {
  int row = blockIdx.x;
  int tid = threadIdx.x;
  const float4* qr = (const float4*)(q + (size_t)row * E_DIM);
  float4 x = qr[tid];
  float s  = x.x + x.y + x.z + x.w;
  float ss = x.x * x.x + x.y * x.y + x.z * x.z + x.w * x.w;
#pragma unroll
  for (int off = 32; off >= 1; off >>= 1) {
    s  += __shfl_xor(s, off, 64);
    ss += __shfl_xor(ss, off, 64);
  }
  __shared__ float red[8];
  int wid = tid >> 6, lane = tid & 63;
  if (lane == 0) { red[wid] = s; red[4 + wid] = ss; }
  __syncthreads();
  s  = red[0] + red[1] + red[2] + red[3];
  ss = red[4] + red[5] + red[6] + red[7];
  float mean = s * (1.0f / E_DIM);
  float var  = ss * (1.0f / E_DIM) - mean * mean;
  float rstd = rsqrtf(var + 1e-5f);
  float4 g4 = ((const float4*)gamma)[tid];
  float4 b4 = ((const float4*)beta)[tid];
  ushort4 o;
  o.x = f2bf((x.x - mean) * rstd * g4.x + b4.x);
  o.y = f2bf((x.y - mean) * rstd * g4.y + b4.y);
  o.z = f2bf((x.z - mean) * rstd * g4.z + b4.z);
  o.w = f2bf((x.w - mean) * rstd * g4.w + b4.w);
  ((ushort4*)(out + (size_t)row * E_DIM))[tid] = o;
}

// ---------------- GEMM: C[M,N] = A[M,K] * Bw[N,K]^T (bf16 in, fp32 acc) ----
template <int MODE>
__global__ __launch_bounds__(256) void gemm_bt_kernel(
    const unsigned short* __restrict__ A, const unsigned short* __restrict__ Bw,
    const float* __restrict__ resid, unsigned short* __restrict__ out_qkv,
    float* __restrict__ out_f, int Kv, int Nv) {
  __shared__ alignas(16) unsigned short lA[128 * 32];
  __shared__ alignas(16) unsigned short lB[128 * 32];
  int tid = threadIdx.x;
  int wid = tid >> 6, lane = tid & 63;
  int wm = wid >> 1, wn = wid & 1;
  int g = lane >> 4, lr = lane & 15;
  int m0 = blockIdx.y * 128, n0 = blockIdx.x * 128;
  f32x4 acc[4][4] = {};

  for (int k0 = 0; k0 < Kv; k0 += 32) {
#pragma unroll
    for (int c = 0; c < 2; ++c) {
      int f16 = c * 256 + tid;
      int row = f16 >> 2, col8 = (f16 & 3) << 3;
      gload_lds16(A  + (size_t)(m0 + row) * Kv + k0 + col8,
                  lA + (size_t)(c * 256 + wid * 64) * 8);
      gload_lds16(Bw + (size_t)(n0 + row) * Kv + k0 + col8,
                  lB + (size_t)(c * 256 + wid * 64) * 8);
    }
    __syncthreads();
    bf16x8 af[4], bfr[4];
#pragma unroll
    for (int r = 0; r < 4; ++r) {
      af[r]  = *(const bf16x8*)(lA + (wm * 64 + r * 16 + lr) * 32 + g * 8);
      bfr[r] = *(const bf16x8*)(lB + (wn * 64 + r * 16 + lr) * 32 + g * 8);
    }
#pragma unroll
    for (int mr = 0; mr < 4; ++mr)
#pragma unroll
      for (int nr = 0; nr < 4; ++nr)
        acc[mr][nr] = __builtin_amdgcn_mfma_f32_16x16x32_bf16(
            af[mr], bfr[nr], acc[mr][nr], 0, 0, 0);
    __syncthreads();
  }

#pragma unroll
  for (int mr = 0; mr < 4; ++mr) {
#pragma unroll
    for (int nr = 0; nr < 4; ++nr) {
#pragma unroll
      for (int r = 0; r < 4; ++r) {
        int grow = m0 + wm * 64 + mr * 16 + g * 4 + r;
        int gcol = n0 + wn * 64 + nr * 16 + lr;
        float v = acc[mr][nr][r];
        if (MODE == 0) {
          int which = gcol >> 10, rem = gcol & 1023;
          int h = rem >> 6, d = rem & 63;
          int t = grow >> 1, b = grow & 1;
          out_qkv[(size_t)which * (BH_DIM * T_DIM * HD_DIM) +
                  ((size_t)(b * H_DIM + h) * T_DIM + t) * HD_DIM + d] = f2bf(v);
        } else {
          size_t idx = (size_t)grow * Nv + gcol;
          out_f[idx] = resid[idx] + v;
        }
      }
    }
  }
}

// ---------------- V transpose: [bh][t][d] -> [bh][d][t] ----------------
__global__ __launch_bounds__(256) void transpose_v_kernel(
    const unsigned short* __restrict__ vb, unsigned short* __restrict__ vt) {
  __shared__ alignas(16) unsigned short tl[64 * 72];
  int tid = threadIdx.x;
  int bh = blockIdx.y, t0 = blockIdx.x * 64;
  const unsigned short* src = vb + ((size_t)bh * T_DIM + t0) * HD_DIM;
#pragma unroll
  for (int e = 0; e < 2; ++e) {
    int i8 = e * 256 + tid;
    int r = i8 >> 3;                  // t-row 0..63
    int c = (i8 & 7) * 8;             // d chunk
    int hsh = (r ^ (r >> 3)) & 7;
    bf16x8 v = *(const bf16x8*)(src + (size_t)r * HD_DIM + c);
    *(bf16x8*)(tl + r * 72 + (c ^ (hsh << 3))) = v;
  }
  __syncthreads();
  unsigned short* dst = vt + (size_t)bh * HD_DIM * T_DIM + t0;
#pragma unroll
  for (int e = 0; e < 2; ++e) {
    int i8 = e * 256 + tid;
    int d = i8 >> 3;                  // d-row 0..63
    int tc = (i8 & 7) * 8;            // t chunk
    u16x8 o;
#pragma unroll
    for (int j = 0; j < 8; ++j) {
      int r = tc + j;
      int hsh = (r ^ (r >> 3)) & 7;
      o[j] = tl[r * 72 + (d ^ (hsh << 3))];
    }
    *(u16x8*)(dst + (size_t)d * T_DIM + tc) = o;
  }
}

// ---------------- Flash attention ----------------
// K tile [64 k][64 d], V^T tile [64 d][64 t], both 128-B rows, LDS-linear.
// Staging: 512 chunks/tile, thread stages chunks {tid, 256+tid}; global source
// pre-swizzled chunk ^= (row&7); reads XOR the same pattern back (rule #21).
__global__ __launch_bounds__(256) void attn_kernel(
    const unsigned short* __restrict__ qb, const unsigned short* __restrict__ kb,
    const unsigned short* __restrict__ vt, unsigned short* __restrict__ ctx) {
  __shared__ alignas(16) unsigned short lK[2][64 * 64];
  __shared__ alignas(16) unsigned short lV[2][64 * 64];
  __shared__ alignas(16) unsigned short lP[4][16 * 72];
  int tid = threadIdx.x;
  int wid = tid >> 6, lane = tid & 63;
  int g = lane >> 4, lr = lane & 15;
  int bh = blockIdx.y;
  int b = bh >> 4, h = bh & 15;
  int qt = blockIdx.x;
  const size_t koff = (size_t)bh * T_DIM * HD_DIM;   // q,k layout [bh][t][64]
  const size_t voff = (size_t)bh * HD_DIM * T_DIM;   // v^T layout [bh][64][T]

  // staging geometry: chunk c = e*256+tid -> row c>>3, phys chunk tid&7.
  // (e*32 rows keep row&7 invariant, so the source swizzle is e-independent)
  int srow = tid >> 3;
  int gch  = (tid & 7) ^ (srow & 7);
  const unsigned short* ks0 = kb + koff + (size_t)srow * HD_DIM + gch * 8;
  const unsigned short* vs0 = vt + voff + (size_t)srow * T_DIM + gch * 8;

#define STAGE_TILE(buf, kofs, vofs)                                            \
  do {                                                                         \
    gload_lds16(ks0 + (kofs),                 lK[buf] + wid * 512);            \
    gload_lds16(ks0 + (kofs) + 32 * HD_DIM,   lK[buf] + 2048 + wid * 512);     \
    gload_lds16(vs0 + (vofs),                 lV[buf] + wid * 512);            \
    gload_lds16(vs0 + (vofs) + (size_t)32 * T_DIM, lV[buf] + 2048 + wid * 512);\
  } while (0)

  // Q fragment, scale 1/8 * log2(e) folded in (softmax uses exp2)
  int qrow = qt * 64 + wid * 16 + lr;
  bf16x8 qf[2];
  {
    const float QS = 0.125f * 1.44269504f;
#pragma unroll
    for (int ks = 0; ks < 2; ++ks) {
      bf16x8 raw = *(const bf16x8*)(qb + koff + (size_t)qrow * HD_DIM + ks * 32 + g * 8);
#pragma unroll
      for (int j = 0; j < 8; ++j) qf[ks][j] = (__bf16)((float)raw[j] * QS);
    }
  }

  f32x4 accO[4] = {};
  float mrun[4], lrun[4];
#pragma unroll
  for (int r = 0; r < 4; ++r) { mrun[r] = -1e30f; lrun[r] = 0.0f; }

  const int NT = T_DIM / 64;  // 32
  STAGE_TILE(0, 0, 0);        // prologue: tile 0

  for (int t = 0; t < NT; ++t) {
    int cur = t & 1;
    if (t + 1 < NT) {
      size_t s1 = (size_t)(t + 1) * 64;
      STAGE_TILE(cur ^ 1, s1 * HD_DIM, s1);
      asm volatile("s_waitcnt vmcnt(4)" ::: "memory");
    } else {
      asm volatile("s_waitcnt vmcnt(0)" ::: "memory");
    }
    __builtin_amdgcn_s_barrier();
    __builtin_amdgcn_sched_barrier(0);

    const unsigned short* Kc = lK[cur];
    const unsigned short* Vc = lV[cur];

    // S = Q K^T (log2-scaled); lane: q-row g*4+r, key cf*16+lr
    float sc[4][4];
#pragma unroll
    for (int cf = 0; cf < 4; ++cf) {
      int row = cf * 16 + lr;
      int sw = (row & 7) << 3;
      bf16x8 k0 = *(const bf16x8*)(Kc + row * 64 + ((g * 8) ^ sw));
      bf16x8 k1 = *(const bf16x8*)(Kc + row * 64 + ((32 + g * 8) ^ sw));
      f32x4 s = {};
      s = __builtin_amdgcn_mfma_f32_16x16x32_bf16(qf[0], k0, s, 0, 0, 0);
      s = __builtin_amdgcn_mfma_f32_16x16x32_bf16(qf[1], k1, s, 0, 0, 0);
#pragma unroll
      for (int r = 0; r < 4; ++r) sc[cf][r] = s[r];
    }

    // online softmax (base-2), wave-parallel over 16-lane key groups
#pragma unroll
    for (int r = 0; r < 4; ++r) {
      float mnew = fmaxf(fmaxf(sc[0][r], sc[1][r]), fmaxf(sc[2][r], sc[3][r]));
#pragma unroll
      for (int off = 8; off >= 1; off >>= 1)
        mnew = fmaxf(mnew, __shfl_xor(mnew, off, 64));
      float mtot  = fmaxf(mrun[r], mnew);
      float alpha = exp2f(mrun[r] - mtot);
      float rs = 0.0f;
#pragma unroll
      for (int cf = 0; cf < 4; ++cf) {
        float p = exp2f(sc[cf][r] - mtot);
        sc[cf][r] = p;
        rs += p;
      }
#pragma unroll
      for (int off = 8; off >= 1; off >>= 1)
        rs += __shfl_xor(rs, off, 64);
      lrun[r] = lrun[r] * alpha + rs;
      mrun[r] = mtot;
#pragma unroll
      for (int df = 0; df < 4; ++df) accO[df][r] *= alpha;
#pragma unroll
      for (int cf = 0; cf < 4; ++cf)
        lP[wid][(g * 4 + r) * 72 + cf * 16 + lr] =
            __builtin_bit_cast(unsigned short, (__bf16)sc[cf][r]);
    }

    // O += P V  (B-operand = V^T rows, swizzled read)
#pragma unroll
    for (int ks = 0; ks < 2; ++ks) {
      bf16x8 pf = *(const bf16x8*)(&lP[wid][lr * 72 + ks * 32 + g * 8]);
#pragma unroll
      for (int df = 0; df < 4; ++df) {
        int row = df * 16 + lr;
        int sw = (row & 7) << 3;
        bf16x8 vf = *(const bf16x8*)(Vc + row * 64 + ((ks * 32 + g * 8) ^ sw));
        accO[df] = __builtin_amdgcn_mfma_f32_16x16x32_bf16(pf, vf, accO[df], 0, 0, 0);
      }
    }
    __builtin_amdgcn_s_barrier();
    __builtin_amdgcn_sched_barrier(0);
  }
#undef STAGE_TILE

  // ctx[t*B+b][h*64+d] bf16
#pragma unroll
  for (int df = 0; df < 4; ++df) {
#pragma unroll
    for (int r = 0; r < 4; ++r) {
      int t = qt * 64 + wid * 16 + g * 4 + r;
      int col = h * HD_DIM + df * 16 + lr;
      float o = accO[df][r] / lrun[r];
      ctx[((size_t)t * B_DIM + b) * E_DIM + col] = f2bf(o);
    }
  }
}

// ---------------- launcher ----------------
extern "C" void kernel_launch(void* const* d_in, const int* in_sizes, int n_in,
                              void* d_out, int out_size, void* d_ws, size_t ws_size,
                              hipStream_t stream) {
  const float* query = (const float*)d_in[0];
  const float* gamma = (const float*)d_in[1];
  const float* beta  = (const float*)d_in[2];
  const float* w_in  = (const float*)d_in[3];
  const float* w_out = (const float*)d_in[4];
  float* out = (float*)d_out;

  unsigned short* ws    = (unsigned short*)d_ws;
  unsigned short* ln    = ws;                                 // 4096*1024 (8 MB)
  unsigned short* winb  = ln + (size_t)M_DIM * E_DIM;         // 3072*1024
  unsigned short* woutb = winb + (size_t)3 * E_DIM * E_DIM;   // 1024*1024
  unsigned short* qkv   = woutb + (size_t)E_DIM * E_DIM;      // 3*32*2048*64

  unsigned short* qbuf = qkv;
  unsigned short* kbuf = qkv + (size_t)BH_DIM * T_DIM * HD_DIM;
  unsigned short* vbuf = kbuf + (size_t)BH_DIM * T_DIM * HD_DIM;
  unsigned short* vtb  = ln;    // reuse: ln consumed by GEMM0 before transpose
  unsigned short* ctx  = vbuf;  // reuse: vbuf consumed by transpose before attn

  cast_bf16_kernel<<<dim3(3072), dim3(256), 0, stream>>>(w_in, winb, 3 * E_DIM * E_DIM / 4);
  cast_bf16_kernel<<<dim3(1024), dim3(256), 0, stream>>>(w_out, woutb, E_DIM * E_DIM / 4);
  ln_kernel<<<dim3(M_DIM), dim3(256), 0, stream>>>(query, gamma, beta, ln);
  gemm_bt_kernel<0><<<dim3(3 * E_DIM / 128, M_DIM / 128), dim3(256), 0, stream>>>(
      ln, winb, nullptr, qkv, nullptr, E_DIM, 3 * E_DIM);
  transpose_v_kernel<<<dim3(T_DIM / 64, BH_DIM), dim3(256), 0, stream>>>(vbuf, vtb);
  attn_kernel<<<dim3(T_DIM / 64, BH_DIM), dim3(256), 0, stream>>>(qbuf, kbuf, vtb, ctx);
  gemm_bt_kernel<1><<<dim3(E_DIM / 128, M_DIM / 128), dim3(256), 0, stream>>>(
      ctx, woutb, query, nullptr, out, E_DIM, E_DIM);
}

// Round 4
// 177.493 us; speedup vs baseline: 1.3855x; 1.2330x over previous
//
#include <hip/hip_runtime.h>
#include <hip/hip_bf16.h>
#include <math.h>

#define T_DIM 2048
#define B_DIM 2
#define E_DIM 1024
#define H_DIM 16
#define HD_DIM 64
#define M_DIM (T_DIM * B_DIM)   // 4096 rows (t*B+b)
#define BH_DIM (B_DIM * H_DIM)  // 32 head-batches

using bf16x8 = __attribute__((ext_vector_type(8))) __bf16;
using u16x8  = __attribute__((ext_vector_type(8))) unsigned short;
using f32x4  = __attribute__((ext_vector_type(4))) float;

static __device__ __forceinline__ unsigned short f2bf(float f) {
  unsigned u = __builtin_bit_cast(unsigned, f);
  u += 0x7fff + ((u >> 16) & 1);   // RNE
  return (unsigned short)(u >> 16);
}

__device__ __forceinline__ void gload_lds16(const void* g, void* l) {
  __builtin_amdgcn_global_load_lds(
      (const __attribute__((address_space(1))) unsigned int*)g,
      (__attribute__((address_space(3))) unsigned int*)l, 16, 0, 0);
}

// ---------------- fp32 -> bf16 cast (weights) ----------------
__global__ __launch_bounds__(256) void cast_bf16_kernel(
    const float* __restrict__ in, unsigned short* __restrict__ out, int n4) {
  int i = blockIdx.x * 256 + threadIdx.x;
  if (i >= n4) return;
  float4 v = ((const float4*)in)[i];
  ushort4 o;
  o.x = f2bf(v.x); o.y = f2bf(v.y); o.z = f2bf(v.z); o.w = f2bf(v.w);
  ((ushort4*)out)[i] = o;
}

// ---------------- LayerNorm (row = one block) ----------------
__global__ __launch_bounds__(256) void ln_kernel(
    const float* __restrict__ q, const float* __restrict__ gamma,
    const float* __restrict__ beta, unsigned short* __restrict__ out) {
  int row = blockIdx.x;
  int tid = threadIdx.x;
  const float4* qr = (const float4*)(q + (size_t)row * E_DIM);
  float4 x = qr[tid];
  float s  = x.x + x.y + x.z + x.w;
  float ss = x.x * x.x + x.y * x.y + x.z * x.z + x.w * x.w;
#pragma unroll
  for (int off = 32; off >= 1; off >>= 1) {
    s  += __shfl_xor(s, off, 64);
    ss += __shfl_xor(ss, off, 64);
  }
  __shared__ float red[8];
  int wid = tid >> 6, lane = tid & 63;
  if (lane == 0) { red[wid] = s; red[4 + wid] = ss; }
  __syncthreads();
  s  = red[0] + red[1] + red[2] + red[3];
  ss = red[4] + red[5] + red[6] + red[7];
  float mean = s * (1.0f / E_DIM);
  float var  = ss * (1.0f / E_DIM) - mean * mean;
  float rstd = rsqrtf(var + 1e-5f);
  float4 g4 = ((const float4*)gamma)[tid];
  float4 b4 = ((const float4*)beta)[tid];
  ushort4 o;
  o.x = f2bf((x.x - mean) * rstd * g4.x + b4.x);
  o.y = f2bf((x.y - mean) * rstd * g4.y + b4.y);
  o.z = f2bf((x.z - mean) * rstd * g4.z + b4.z);
  o.w = f2bf((x.w - mean) * rstd * g4.w + b4.w);
  ((ushort4*)(out + (size_t)row * E_DIM))[tid] = o;
}

// ---------------- GEMM: C[M,N] = A[M,K] * Bw[N,K]^T (bf16 in, fp32 acc) ----
template <int MODE>
__global__ __launch_bounds__(256) void gemm_bt_kernel(
    const unsigned short* __restrict__ A, const unsigned short* __restrict__ Bw,
    const float* __restrict__ resid, unsigned short* __restrict__ out_qkv,
    float* __restrict__ out_f, int Kv, int Nv) {
  __shared__ alignas(16) unsigned short lA[128 * 32];
  __shared__ alignas(16) unsigned short lB[128 * 32];
  int tid = threadIdx.x;
  int wid = tid >> 6, lane = tid & 63;
  int wm = wid >> 1, wn = wid & 1;
  int g = lane >> 4, lr = lane & 15;
  int m0 = blockIdx.y * 128, n0 = blockIdx.x * 128;
  f32x4 acc[4][4] = {};

  for (int k0 = 0; k0 < Kv; k0 += 32) {
#pragma unroll
    for (int c = 0; c < 2; ++c) {
      int f16 = c * 256 + tid;
      int row = f16 >> 2, col8 = (f16 & 3) << 3;
      gload_lds16(A  + (size_t)(m0 + row) * Kv + k0 + col8,
                  lA + (size_t)(c * 256 + wid * 64) * 8);
      gload_lds16(Bw + (size_t)(n0 + row) * Kv + k0 + col8,
                  lB + (size_t)(c * 256 + wid * 64) * 8);
    }
    __syncthreads();
    bf16x8 af[4], bfr[4];
#pragma unroll
    for (int r = 0; r < 4; ++r) {
      af[r]  = *(const bf16x8*)(lA + (wm * 64 + r * 16 + lr) * 32 + g * 8);
      bfr[r] = *(const bf16x8*)(lB + (wn * 64 + r * 16 + lr) * 32 + g * 8);
    }
#pragma unroll
    for (int mr = 0; mr < 4; ++mr)
#pragma unroll
      for (int nr = 0; nr < 4; ++nr)
        acc[mr][nr] = __builtin_amdgcn_mfma_f32_16x16x32_bf16(
            af[mr], bfr[nr], acc[mr][nr], 0, 0, 0);
    __syncthreads();
  }

#pragma unroll
  for (int mr = 0; mr < 4; ++mr) {
#pragma unroll
    for (int nr = 0; nr < 4; ++nr) {
#pragma unroll
      for (int r = 0; r < 4; ++r) {
        int grow = m0 + wm * 64 + mr * 16 + g * 4 + r;
        int gcol = n0 + wn * 64 + nr * 16 + lr;
        float v = acc[mr][nr][r];
        if (MODE == 0) {
          int which = gcol >> 10, rem = gcol & 1023;
          int h = rem >> 6, d = rem & 63;
          int t = grow >> 1, b = grow & 1;
          out_qkv[(size_t)which * (BH_DIM * T_DIM * HD_DIM) +
                  ((size_t)(b * H_DIM + h) * T_DIM + t) * HD_DIM + d] = f2bf(v);
        } else {
          size_t idx = (size_t)grow * Nv + gcol;
          out_f[idx] = resid[idx] + v;
        }
      }
    }
  }
}

// ---------------- V transpose: [bh][t][d] -> [bh][d][t] ----------------
__global__ __launch_bounds__(256) void transpose_v_kernel(
    const unsigned short* __restrict__ vb, unsigned short* __restrict__ vt) {
  __shared__ alignas(16) unsigned short tl[64 * 72];
  int tid = threadIdx.x;
  int bh = blockIdx.y, t0 = blockIdx.x * 64;
  const unsigned short* src = vb + ((size_t)bh * T_DIM + t0) * HD_DIM;
#pragma unroll
  for (int e = 0; e < 2; ++e) {
    int i8 = e * 256 + tid;
    int r = i8 >> 3;                  // t-row 0..63
    int c = (i8 & 7) * 8;             // d chunk
    int hsh = (r ^ (r >> 3)) & 7;
    bf16x8 v = *(const bf16x8*)(src + (size_t)r * HD_DIM + c);
    *(bf16x8*)(tl + r * 72 + (c ^ (hsh << 3))) = v;
  }
  __syncthreads();
  unsigned short* dst = vt + (size_t)bh * HD_DIM * T_DIM + t0;
#pragma unroll
  for (int e = 0; e < 2; ++e) {
    int i8 = e * 256 + tid;
    int d = i8 >> 3;                  // d-row 0..63
    int tc = (i8 & 7) * 8;            // t chunk
    u16x8 o;
#pragma unroll
    for (int j = 0; j < 8; ++j) {
      int r = tc + j;
      int hsh = (r ^ (r >> 3)) & 7;
      o[j] = tl[r * 72 + (d ^ (hsh << 3))];
    }
    *(u16x8*)(dst + (size_t)d * T_DIM + tc) = o;
  }
}

// ---------------- Flash attention (fixed-max softmax, MFMA row-sum) -------
// K tile [64 k][64 d], V^T tile [64 d][64 t], both 128-B rows, LDS-linear.
// Staging: 512 chunks/tile, source pre-swizzled chunk ^= (row&7); reads XOR
// the same pattern back (rule #21).
// Softmax: P = 2^(qk*QS - 8) with CONSTANT max (exact: scale cancels in
// accO/accS). Row-sum accS accumulated by an extra MFMA with all-ones B.
__global__ __launch_bounds__(256) void attn_kernel(
    const unsigned short* __restrict__ qb, const unsigned short* __restrict__ kb,
    const unsigned short* __restrict__ vt, unsigned short* __restrict__ ctx) {
  __shared__ alignas(16) unsigned short lK[2][64 * 64];
  __shared__ alignas(16) unsigned short lV[2][64 * 64];
  __shared__ alignas(16) unsigned short lP[4][16 * 72];
  int tid = threadIdx.x;
  int wid = tid >> 6, lane = tid & 63;
  int g = lane >> 4, lr = lane & 15;
  int bh = blockIdx.y;
  int b = bh >> 4, h = bh & 15;
  int qt = blockIdx.x;
  const size_t koff = (size_t)bh * T_DIM * HD_DIM;   // q,k layout [bh][t][64]
  const size_t voff = (size_t)bh * HD_DIM * T_DIM;   // v^T layout [bh][64][T]

  int srow = tid >> 3;
  int gch  = (tid & 7) ^ (srow & 7);
  const unsigned short* ks0 = kb + koff + (size_t)srow * HD_DIM + gch * 8;
  const unsigned short* vs0 = vt + voff + (size_t)srow * T_DIM + gch * 8;

#define STAGE_TILE(buf, kofs, vofs)                                            \
  do {                                                                         \
    gload_lds16(ks0 + (kofs),                 lK[buf] + wid * 512);            \
    gload_lds16(ks0 + (kofs) + 32 * HD_DIM,   lK[buf] + 2048 + wid * 512);     \
    gload_lds16(vs0 + (vofs),                 lV[buf] + wid * 512);            \
    gload_lds16(vs0 + (vofs) + (size_t)32 * T_DIM, lV[buf] + 2048 + wid * 512);\
  } while (0)

  // Q fragment, scale 1/8 * log2(e) folded in (softmax uses exp2)
  int qrow = qt * 64 + wid * 16 + lr;
  bf16x8 qf[2];
  {
    const float QS = 0.125f * 1.44269504f;
#pragma unroll
    for (int ks = 0; ks < 2; ++ks) {
      bf16x8 raw = *(const bf16x8*)(qb + koff + (size_t)qrow * HD_DIM + ks * 32 + g * 8);
#pragma unroll
      for (int j = 0; j < 8; ++j) qf[ks][j] = (__bf16)((float)raw[j] * QS);
    }
  }

  bf16x8 onesf;
#pragma unroll
  for (int j = 0; j < 8; ++j) onesf[j] = (__bf16)1.0f;

  f32x4 accO[4] = {};
  f32x4 accS = {};

  const int NT = T_DIM / 64;  // 32
  STAGE_TILE(0, 0, 0);        // prologue: tile 0

  for (int t = 0; t < NT; ++t) {
    int cur = t & 1;
    if (t + 1 < NT) {
      size_t s1 = (size_t)(t + 1) * 64;
      STAGE_TILE(cur ^ 1, s1 * HD_DIM, s1);
      asm volatile("s_waitcnt vmcnt(4)" ::: "memory");
    } else {
      asm volatile("s_waitcnt vmcnt(0)" ::: "memory");
    }
    __builtin_amdgcn_s_barrier();
    __builtin_amdgcn_sched_barrier(0);

    const unsigned short* Kc = lK[cur];
    const unsigned short* Vc = lV[cur];

    // S = Q K^T * QS - 8 (log2 domain, -8 folded into MFMA C-init)
    f32x4 s4[4];
    __builtin_amdgcn_s_setprio(1);
#pragma unroll
    for (int cf = 0; cf < 4; ++cf) {
      int row = cf * 16 + lr;
      int sw = (row & 7) << 3;
      bf16x8 k0 = *(const bf16x8*)(Kc + row * 64 + ((g * 8) ^ sw));
      bf16x8 k1 = *(const bf16x8*)(Kc + row * 64 + ((32 + g * 8) ^ sw));
      f32x4 s = {-8.0f, -8.0f, -8.0f, -8.0f};
      s = __builtin_amdgcn_mfma_f32_16x16x32_bf16(qf[0], k0, s, 0, 0, 0);
      s = __builtin_amdgcn_mfma_f32_16x16x32_bf16(qf[1], k1, s, 0, 0, 0);
      s4[cf] = s;
    }
    __builtin_amdgcn_s_setprio(0);

    // P = exp2(S), straight to LDS (no reductions, no rescale)
#pragma unroll
    for (int cf = 0; cf < 4; ++cf)
#pragma unroll
      for (int r = 0; r < 4; ++r)
        lP[wid][(g * 4 + r) * 72 + cf * 16 + lr] =
            __builtin_bit_cast(unsigned short, (__bf16)exp2f(s4[cf][r]));

    // O += P V ; rowsum += P * ones
    __builtin_amdgcn_s_setprio(1);
#pragma unroll
    for (int ks = 0; ks < 2; ++ks) {
      bf16x8 pf = *(const bf16x8*)(&lP[wid][lr * 72 + ks * 32 + g * 8]);
      accS = __builtin_amdgcn_mfma_f32_16x16x32_bf16(pf, onesf, accS, 0, 0, 0);
#pragma unroll
      for (int df = 0; df < 4; ++df) {
        int row = df * 16 + lr;
        int sw = (row & 7) << 3;
        bf16x8 vf = *(const bf16x8*)(Vc + row * 64 + ((ks * 32 + g * 8) ^ sw));
        accO[df] = __builtin_amdgcn_mfma_f32_16x16x32_bf16(pf, vf, accO[df], 0, 0, 0);
      }
    }
    __builtin_amdgcn_s_setprio(0);
    __builtin_amdgcn_s_barrier();
    __builtin_amdgcn_sched_barrier(0);
  }
#undef STAGE_TILE

  // ctx[t*B+b][h*64+d] bf16
  float invl[4];
#pragma unroll
  for (int r = 0; r < 4; ++r) invl[r] = 1.0f / accS[r];
#pragma unroll
  for (int df = 0; df < 4; ++df) {
#pragma unroll
    for (int r = 0; r < 4; ++r) {
      int t = qt * 64 + wid * 16 + g * 4 + r;
      int col = h * HD_DIM + df * 16 + lr;
      float o = accO[df][r] * invl[r];
      ctx[((size_t)t * B_DIM + b) * E_DIM + col] = f2bf(o);
    }
  }
}

// ---------------- launcher ----------------
extern "C" void kernel_launch(void* const* d_in, const int* in_sizes, int n_in,
                              void* d_out, int out_size, void* d_ws, size_t ws_size,
                              hipStream_t stream) {
  const float* query = (const float*)d_in[0];
  const float* gamma = (const float*)d_in[1];
  const float* beta  = (const float*)d_in[2];
  const float* w_in  = (const float*)d_in[3];
  const float* w_out = (const float*)d_in[4];
  float* out = (float*)d_out;

  unsigned short* ws    = (unsigned short*)d_ws;
  unsigned short* ln    = ws;                                 // 4096*1024 (8 MB)
  unsigned short* winb  = ln + (size_t)M_DIM * E_DIM;         // 3072*1024
  unsigned short* woutb = winb + (size_t)3 * E_DIM * E_DIM;   // 1024*1024
  unsigned short* qkv   = woutb + (size_t)E_DIM * E_DIM;      // 3*32*2048*64

  unsigned short* qbuf = qkv;
  unsigned short* kbuf = qkv + (size_t)BH_DIM * T_DIM * HD_DIM;
  unsigned short* vbuf = kbuf + (size_t)BH_DIM * T_DIM * HD_DIM;
  unsigned short* vtb  = ln;    // reuse: ln consumed by GEMM0 before transpose
  unsigned short* ctx  = vbuf;  // reuse: vbuf consumed by transpose before attn

  cast_bf16_kernel<<<dim3(3072), dim3(256), 0, stream>>>(w_in, winb, 3 * E_DIM * E_DIM / 4);
  cast_bf16_kernel<<<dim3(1024), dim3(256), 0, stream>>>(w_out, woutb, E_DIM * E_DIM / 4);
  ln_kernel<<<dim3(M_DIM), dim3(256), 0, stream>>>(query, gamma, beta, ln);
  gemm_bt_kernel<0><<<dim3(3 * E_DIM / 128, M_DIM / 128), dim3(256), 0, stream>>>(
      ln, winb, nullptr, qkv, nullptr, E_DIM, 3 * E_DIM);
  transpose_v_kernel<<<dim3(T_DIM / 64, BH_DIM), dim3(256), 0, stream>>>(vbuf, vtb);
  attn_kernel<<<dim3(T_DIM / 64, BH_DIM), dim3(256), 0, stream>>>(qbuf, kbuf, vtb, ctx);
  gemm_bt_kernel<1><<<dim3(E_DIM / 128, M_DIM / 128), dim3(256), 0, stream>>>(
      ctx, woutb, query, nullptr, out, E_DIM, E_DIM);
}

// Round 5
// 161.032 us; speedup vs baseline: 1.5271x; 1.1022x over previous
//
#include <hip/hip_runtime.h>
#include <hip/hip_bf16.h>
#include <math.h>

#define T_DIM 2048
#define B_DIM 2
#define E_DIM 1024
#define H_DIM 16
#define HD_DIM 64
#define M_DIM (T_DIM * B_DIM)   // 4096 rows (t*B+b)
#define BH_DIM (B_DIM * H_DIM)  // 32 head-batches

using bf16x8 = __attribute__((ext_vector_type(8))) __bf16;
using u16x8  = __attribute__((ext_vector_type(8))) unsigned short;
using f32x4  = __attribute__((ext_vector_type(4))) float;

static __device__ __forceinline__ unsigned short f2bf(float f) {
  unsigned u = __builtin_bit_cast(unsigned, f);
  u += 0x7fff + ((u >> 16) & 1);   // RNE
  return (unsigned short)(u >> 16);
}

__device__ __forceinline__ void gload_lds16(const void* g, void* l) {
  __builtin_amdgcn_global_load_lds(
      (const __attribute__((address_space(1))) unsigned int*)g,
      (__attribute__((address_space(3))) unsigned int*)l, 16, 0, 0);
}

// ---------------- fp32 -> bf16 cast (weights) ----------------
__global__ __launch_bounds__(256) void cast_bf16_kernel(
    const float* __restrict__ in, unsigned short* __restrict__ out, int n4) {
  int i = blockIdx.x * 256 + threadIdx.x;
  if (i >= n4) return;
  float4 v = ((const float4*)in)[i];
  ushort4 o;
  o.x = f2bf(v.x); o.y = f2bf(v.y); o.z = f2bf(v.z); o.w = f2bf(v.w);
  ((ushort4*)out)[i] = o;
}

// ---------------- LayerNorm (row = one block) ----------------
__global__ __launch_bounds__(256) void ln_kernel(
    const float* __restrict__ q, const float* __restrict__ gamma,
    const float* __restrict__ beta, unsigned short* __restrict__ out) {
  int row = blockIdx.x;
  int tid = threadIdx.x;
  const float4* qr = (const float4*)(q + (size_t)row * E_DIM);
  float4 x = qr[tid];
  float s  = x.x + x.y + x.z + x.w;
  float ss = x.x * x.x + x.y * x.y + x.z * x.z + x.w * x.w;
#pragma unroll
  for (int off = 32; off >= 1; off >>= 1) {
    s  += __shfl_xor(s, off, 64);
    ss += __shfl_xor(ss, off, 64);
  }
  __shared__ float red[8];
  int wid = tid >> 6, lane = tid & 63;
  if (lane == 0) { red[wid] = s; red[4 + wid] = ss; }
  __syncthreads();
  s  = red[0] + red[1] + red[2] + red[3];
  ss = red[4] + red[5] + red[6] + red[7];
  float mean = s * (1.0f / E_DIM);
  float var  = ss * (1.0f / E_DIM) - mean * mean;
  float rstd = rsqrtf(var + 1e-5f);
  float4 g4 = ((const float4*)gamma)[tid];
  float4 b4 = ((const float4*)beta)[tid];
  ushort4 o;
  o.x = f2bf((x.x - mean) * rstd * g4.x + b4.x);
  o.y = f2bf((x.y - mean) * rstd * g4.y + b4.y);
  o.z = f2bf((x.z - mean) * rstd * g4.z + b4.z);
  o.w = f2bf((x.w - mean) * rstd * g4.w + b4.w);
  ((ushort4*)(out + (size_t)row * E_DIM))[tid] = o;
}

// ---------------- GEMM: C[M,N] = A[M,K] * Bw[N,K]^T (bf16 in, fp32 acc) ----
template <int MODE>
__global__ __launch_bounds__(256) void gemm_bt_kernel(
    const unsigned short* __restrict__ A, const unsigned short* __restrict__ Bw,
    const float* __restrict__ resid, unsigned short* __restrict__ out_qkv,
    float* __restrict__ out_f, int Kv, int Nv) {
  __shared__ alignas(16) unsigned short lA[128 * 32];
  __shared__ alignas(16) unsigned short lB[128 * 32];
  int tid = threadIdx.x;
  int wid = tid >> 6, lane = tid & 63;
  int wm = wid >> 1, wn = wid & 1;
  int g = lane >> 4, lr = lane & 15;
  int m0 = blockIdx.y * 128, n0 = blockIdx.x * 128;
  f32x4 acc[4][4] = {};

  for (int k0 = 0; k0 < Kv; k0 += 32) {
#pragma unroll
    for (int c = 0; c < 2; ++c) {
      int f16 = c * 256 + tid;
      int row = f16 >> 2, col8 = (f16 & 3) << 3;
      gload_lds16(A  + (size_t)(m0 + row) * Kv + k0 + col8,
                  lA + (size_t)(c * 256 + wid * 64) * 8);
      gload_lds16(Bw + (size_t)(n0 + row) * Kv + k0 + col8,
                  lB + (size_t)(c * 256 + wid * 64) * 8);
    }
    __syncthreads();
    bf16x8 af[4], bfr[4];
#pragma unroll
    for (int r = 0; r < 4; ++r) {
      af[r]  = *(const bf16x8*)(lA + (wm * 64 + r * 16 + lr) * 32 + g * 8);
      bfr[r] = *(const bf16x8*)(lB + (wn * 64 + r * 16 + lr) * 32 + g * 8);
    }
#pragma unroll
    for (int mr = 0; mr < 4; ++mr)
#pragma unroll
      for (int nr = 0; nr < 4; ++nr)
        acc[mr][nr] = __builtin_amdgcn_mfma_f32_16x16x32_bf16(
            af[mr], bfr[nr], acc[mr][nr], 0, 0, 0);
    __syncthreads();
  }

#pragma unroll
  for (int mr = 0; mr < 4; ++mr) {
#pragma unroll
    for (int nr = 0; nr < 4; ++nr) {
#pragma unroll
      for (int r = 0; r < 4; ++r) {
        int grow = m0 + wm * 64 + mr * 16 + g * 4 + r;
        int gcol = n0 + wn * 64 + nr * 16 + lr;
        float v = acc[mr][nr][r];
        if (MODE == 0) {
          int which = gcol >> 10, rem = gcol & 1023;
          int h = rem >> 6, d = rem & 63;
          int t = grow >> 1, b = grow & 1;
          out_qkv[(size_t)which * (BH_DIM * T_DIM * HD_DIM) +
                  ((size_t)(b * H_DIM + h) * T_DIM + t) * HD_DIM + d] = f2bf(v);
        } else {
          size_t idx = (size_t)grow * Nv + gcol;
          out_f[idx] = resid[idx] + v;
        }
      }
    }
  }
}

// ---------------- V transpose: [bh][t][d] -> [bh][d][t] ----------------
__global__ __launch_bounds__(256) void transpose_v_kernel(
    const unsigned short* __restrict__ vb, unsigned short* __restrict__ vt) {
  __shared__ alignas(16) unsigned short tl[64 * 72];
  int tid = threadIdx.x;
  int bh = blockIdx.y, t0 = blockIdx.x * 64;
  const unsigned short* src = vb + ((size_t)bh * T_DIM + t0) * HD_DIM;
#pragma unroll
  for (int e = 0; e < 2; ++e) {
    int i8 = e * 256 + tid;
    int r = i8 >> 3;                  // t-row 0..63
    int c = (i8 & 7) * 8;             // d chunk
    int hsh = (r ^ (r >> 3)) & 7;
    bf16x8 v = *(const bf16x8*)(src + (size_t)r * HD_DIM + c);
    *(bf16x8*)(tl + r * 72 + (c ^ (hsh << 3))) = v;
  }
  __syncthreads();
  unsigned short* dst = vt + (size_t)bh * HD_DIM * T_DIM + t0;
#pragma unroll
  for (int e = 0; e < 2; ++e) {
    int i8 = e * 256 + tid;
    int d = i8 >> 3;                  // d-row 0..63
    int tc = (i8 & 7) * 8;            // t chunk
    u16x8 o;
#pragma unroll
    for (int j = 0; j < 8; ++j) {
      int r = tc + j;
      int hsh = (r ^ (r >> 3)) & 7;
      o[j] = tl[r * 72 + (d ^ (hsh << 3))];
    }
    *(u16x8*)(dst + (size_t)d * T_DIM + tc) = o;
  }
}

// ---------------- Flash attention (fixed-max softmax, MFMA row-sum) -------
// Per wave: 32 q-rows (2 q-frags). Block: 128 q-rows. KV tile 64.
// K tile [64 k][64 d], V^T tile [64 d][64 t], both 128-B rows, LDS-linear.
// Staging via global_load_lds, source pre-swizzled chunk ^= (row&7); reads
// XOR the same pattern back (rule #21). Manual 2x unroll makes the buffer
// index compile-time so LDS read addresses are loop-invariant.
__global__ __launch_bounds__(256) void attn_kernel(
    const unsigned short* __restrict__ qb, const unsigned short* __restrict__ kb,
    const unsigned short* __restrict__ vt, unsigned short* __restrict__ ctx) {
  __shared__ alignas(16) unsigned short lK[2][64 * 64];
  __shared__ alignas(16) unsigned short lV[2][64 * 64];
  __shared__ alignas(16) unsigned short lP[4][32 * 72];
  int tid = threadIdx.x;
  int wid = tid >> 6, lane = tid & 63;
  int g = lane >> 4, lr = lane & 15;
  int bh = blockIdx.y;
  int b = bh >> 4, h = bh & 15;
  int qt = blockIdx.x;
  const size_t koff = (size_t)bh * T_DIM * HD_DIM;   // q,k layout [bh][t][64]
  const size_t voff = (size_t)bh * HD_DIM * T_DIM;   // v^T layout [bh][64][T]

  int srow = tid >> 3;
  int gch  = (tid & 7) ^ (srow & 7);
  const unsigned short* ks0 = kb + koff + (size_t)srow * HD_DIM + gch * 8;
  const unsigned short* vs0 = vt + voff + (size_t)srow * T_DIM + gch * 8;

#define STAGE_TILE(buf, kofs, vofs)                                            \
  do {                                                                         \
    gload_lds16(ks0 + (kofs),                 lK[buf] + wid * 512);            \
    gload_lds16(ks0 + (kofs) + 32 * HD_DIM,   lK[buf] + 2048 + wid * 512);     \
    gload_lds16(vs0 + (vofs),                 lV[buf] + wid * 512);            \
    gload_lds16(vs0 + (vofs) + (size_t)32 * T_DIM, lV[buf] + 2048 + wid * 512);\
  } while (0)

  // Q fragments (32 rows/wave), scale 1/8 * log2(e) folded in
  bf16x8 qf[2][2];
  {
    const float QS = 0.125f * 1.44269504f;
#pragma unroll
    for (int qa = 0; qa < 2; ++qa) {
      int qrow = qt * 128 + wid * 32 + qa * 16 + lr;
#pragma unroll
      for (int ks = 0; ks < 2; ++ks) {
        bf16x8 raw = *(const bf16x8*)(qb + koff + (size_t)qrow * HD_DIM + ks * 32 + g * 8);
#pragma unroll
        for (int j = 0; j < 8; ++j) qf[qa][ks][j] = (__bf16)((float)raw[j] * QS);
      }
    }
  }

  bf16x8 onesf;
#pragma unroll
  for (int j = 0; j < 8; ++j) onesf[j] = (__bf16)1.0f;

  f32x4 accO[2][4] = {};
  f32x4 accS[2] = {};

  const int NT = T_DIM / 64;  // 32
  STAGE_TILE(0, 0, 0);        // prologue: tile 0

#define PROCESS(BUF, TT, LAST)                                                 \
  do {                                                                         \
    if (!(LAST)) {                                                             \
      size_t s1 = (size_t)((TT) + 1) * 64;                                     \
      STAGE_TILE((BUF) ^ 1, s1 * HD_DIM, s1);                                  \
      asm volatile("s_waitcnt vmcnt(4)" ::: "memory");                         \
    } else {                                                                   \
      asm volatile("s_waitcnt vmcnt(0)" ::: "memory");                         \
    }                                                                          \
    __builtin_amdgcn_s_barrier();                                              \
    __builtin_amdgcn_sched_barrier(0);                                         \
    const unsigned short* Kc = lK[BUF];                                        \
    const unsigned short* Vc = lV[BUF];                                        \
    f32x4 s4[2][4];                                                            \
    __builtin_amdgcn_s_setprio(1);                                             \
    _Pragma("unroll")                                                          \
    for (int cf = 0; cf < 4; ++cf) {                                           \
      int row = cf * 16 + lr;                                                  \
      int sw = (row & 7) << 3;                                                 \
      bf16x8 k0 = *(const bf16x8*)(Kc + row * 64 + ((g * 8) ^ sw));            \
      bf16x8 k1 = *(const bf16x8*)(Kc + row * 64 + ((32 + g * 8) ^ sw));       \
      _Pragma("unroll")                                                        \
      for (int qa = 0; qa < 2; ++qa) {                                         \
        f32x4 s = {-8.0f, -8.0f, -8.0f, -8.0f};                                \
        s = __builtin_amdgcn_mfma_f32_16x16x32_bf16(qf[qa][0], k0, s, 0, 0, 0);\
        s = __builtin_amdgcn_mfma_f32_16x16x32_bf16(qf[qa][1], k1, s, 0, 0, 0);\
        s4[qa][cf] = s;                                                        \
      }                                                                        \
    }                                                                          \
    __builtin_amdgcn_s_setprio(0);                                             \
    _Pragma("unroll")                                                          \
    for (int qa = 0; qa < 2; ++qa)                                             \
      _Pragma("unroll")                                                        \
      for (int cf = 0; cf < 4; ++cf)                                           \
        _Pragma("unroll")                                                      \
        for (int r = 0; r < 4; ++r)                                            \
          lP[wid][(qa * 16 + g * 4 + r) * 72 + cf * 16 + lr] =                 \
              __builtin_bit_cast(unsigned short, (__bf16)exp2f(s4[qa][cf][r]));\
    __builtin_amdgcn_s_setprio(1);                                             \
    _Pragma("unroll")                                                          \
    for (int ks = 0; ks < 2; ++ks) {                                           \
      bf16x8 pf[2];                                                            \
      _Pragma("unroll")                                                        \
      for (int qa = 0; qa < 2; ++qa) {                                         \
        pf[qa] = *(const bf16x8*)(&lP[wid][(qa * 16 + lr) * 72 + ks * 32 + g * 8]); \
        accS[qa] = __builtin_amdgcn_mfma_f32_16x16x32_bf16(pf[qa], onesf, accS[qa], 0, 0, 0); \
      }                                                                        \
      _Pragma("unroll")                                                        \
      for (int df = 0; df < 4; ++df) {                                         \
        int row = df * 16 + lr;                                                \
        int sw = (row & 7) << 3;                                               \
        bf16x8 vf = *(const bf16x8*)(Vc + row * 64 + ((ks * 32 + g * 8) ^ sw));\
        _Pragma("unroll")                                                      \
        for (int qa = 0; qa < 2; ++qa)                                         \
          accO[qa][df] = __builtin_amdgcn_mfma_f32_16x16x32_bf16(pf[qa], vf, accO[qa][df], 0, 0, 0); \
      }                                                                        \
    }                                                                          \
    __builtin_amdgcn_s_setprio(0);                                             \
    __builtin_amdgcn_s_barrier();                                              \
    __builtin_amdgcn_sched_barrier(0);                                         \
  } while (0)

  for (int t2 = 0; t2 < NT; t2 += 2) {
    PROCESS(0, t2, false);
    PROCESS(1, t2 + 1, t2 + 2 >= NT);
  }
#undef PROCESS
#undef STAGE_TILE

  // ctx[t*B+b][h*64+d] bf16
#pragma unroll
  for (int qa = 0; qa < 2; ++qa) {
    float invl[4];
#pragma unroll
    for (int r = 0; r < 4; ++r) invl[r] = 1.0f / accS[qa][r];
#pragma unroll
    for (int df = 0; df < 4; ++df) {
#pragma unroll
      for (int r = 0; r < 4; ++r) {
        int t = qt * 128 + wid * 32 + qa * 16 + g * 4 + r;
        int col = h * HD_DIM + df * 16 + lr;
        float o = accO[qa][df][r] * invl[r];
        ctx[((size_t)t * B_DIM + b) * E_DIM + col] = f2bf(o);
      }
    }
  }
}

// ---------------- launcher ----------------
extern "C" void kernel_launch(void* const* d_in, const int* in_sizes, int n_in,
                              void* d_out, int out_size, void* d_ws, size_t ws_size,
                              hipStream_t stream) {
  const float* query = (const float*)d_in[0];
  const float* gamma = (const float*)d_in[1];
  const float* beta  = (const float*)d_in[2];
  const float* w_in  = (const float*)d_in[3];
  const float* w_out = (const float*)d_in[4];
  float* out = (float*)d_out;

  unsigned short* ws    = (unsigned short*)d_ws;
  unsigned short* ln    = ws;                                 // 4096*1024 (8 MB)
  unsigned short* winb  = ln + (size_t)M_DIM * E_DIM;         // 3072*1024
  unsigned short* woutb = winb + (size_t)3 * E_DIM * E_DIM;   // 1024*1024
  unsigned short* qkv   = woutb + (size_t)E_DIM * E_DIM;      // 3*32*2048*64

  unsigned short* qbuf = qkv;
  unsigned short* kbuf = qkv + (size_t)BH_DIM * T_DIM * HD_DIM;
  unsigned short* vbuf = kbuf + (size_t)BH_DIM * T_DIM * HD_DIM;
  unsigned short* vtb  = ln;    // reuse: ln consumed by GEMM0 before transpose
  unsigned short* ctx  = vbuf;  // reuse: vbuf consumed by transpose before attn

  cast_bf16_kernel<<<dim3(3072), dim3(256), 0, stream>>>(w_in, winb, 3 * E_DIM * E_DIM / 4);
  cast_bf16_kernel<<<dim3(1024), dim3(256), 0, stream>>>(w_out, woutb, E_DIM * E_DIM / 4);
  ln_kernel<<<dim3(M_DIM), dim3(256), 0, stream>>>(query, gamma, beta, ln);
  gemm_bt_kernel<0><<<dim3(3 * E_DIM / 128, M_DIM / 128), dim3(256), 0, stream>>>(
      ln, winb, nullptr, qkv, nullptr, E_DIM, 3 * E_DIM);
  transpose_v_kernel<<<dim3(T_DIM / 64, BH_DIM), dim3(256), 0, stream>>>(vbuf, vtb);
  attn_kernel<<<dim3(T_DIM / 128, BH_DIM), dim3(256), 0, stream>>>(qbuf, kbuf, vtb, ctx);
  gemm_bt_kernel<1><<<dim3(E_DIM / 128, M_DIM / 128), dim3(256), 0, stream>>>(
      ctx, woutb, query, nullptr, out, E_DIM, E_DIM);
}

// Round 6
// 137.712 us; speedup vs baseline: 1.7857x; 1.1693x over previous
//
#include <hip/hip_runtime.h>
#include <hip/hip_bf16.h>
#include <math.h>

#define T_DIM 2048
#define B_DIM 2
#define E_DIM 1024
#define H_DIM 16
#define HD_DIM 64
#define M_DIM (T_DIM * B_DIM)   // 4096 rows (t*B+b)
#define BH_DIM (B_DIM * H_DIM)  // 32 head-batches

using bf16x8 = __attribute__((ext_vector_type(8))) __bf16;
using u16x8  = __attribute__((ext_vector_type(8))) unsigned short;
using u16x4  = __attribute__((ext_vector_type(4))) unsigned short;
using f32x4  = __attribute__((ext_vector_type(4))) float;

static __device__ __forceinline__ unsigned short f2bf(float f) {
  unsigned u = __builtin_bit_cast(unsigned, f);
  u += 0x7fff + ((u >> 16) & 1);   // RNE
  return (unsigned short)(u >> 16);
}

__device__ __forceinline__ void gload_lds16(const void* g, void* l) {
  __builtin_amdgcn_global_load_lds(
      (const __attribute__((address_space(1))) unsigned int*)g,
      (__attribute__((address_space(3))) unsigned int*)l, 16, 0, 0);
}

// ---------------- fp32 -> bf16 cast (weights) ----------------
__global__ __launch_bounds__(256) void cast_bf16_kernel(
    const float* __restrict__ in, unsigned short* __restrict__ out, int n4) {
  int i = blockIdx.x * 256 + threadIdx.x;
  if (i >= n4) return;
  float4 v = ((const float4*)in)[i];
  ushort4 o;
  o.x = f2bf(v.x); o.y = f2bf(v.y); o.z = f2bf(v.z); o.w = f2bf(v.w);
  ((ushort4*)out)[i] = o;
}

// ---------------- LayerNorm (row = one block) ----------------
__global__ __launch_bounds__(256) void ln_kernel(
    const float* __restrict__ q, const float* __restrict__ gamma,
    const float* __restrict__ beta, unsigned short* __restrict__ out) {
  int row = blockIdx.x;
  int tid = threadIdx.x;
  const float4* qr = (const float4*)(q + (size_t)row * E_DIM);
  float4 x = qr[tid];
  float s  = x.x + x.y + x.z + x.w;
  float ss = x.x * x.x + x.y * x.y + x.z * x.z + x.w * x.w;
#pragma unroll
  for (int off = 32; off >= 1; off >>= 1) {
    s  += __shfl_xor(s, off, 64);
    ss += __shfl_xor(ss, off, 64);
  }
  __shared__ float red[8];
  int wid = tid >> 6, lane = tid & 63;
  if (lane == 0) { red[wid] = s; red[4 + wid] = ss; }
  __syncthreads();
  s  = red[0] + red[1] + red[2] + red[3];
  ss = red[4] + red[5] + red[6] + red[7];
  float mean = s * (1.0f / E_DIM);
  float var  = ss * (1.0f / E_DIM) - mean * mean;
  float rstd = rsqrtf(var + 1e-5f);
  float4 g4 = ((const float4*)gamma)[tid];
  float4 b4 = ((const float4*)beta)[tid];
  ushort4 o;
  o.x = f2bf((x.x - mean) * rstd * g4.x + b4.x);
  o.y = f2bf((x.y - mean) * rstd * g4.y + b4.y);
  o.z = f2bf((x.z - mean) * rstd * g4.z + b4.z);
  o.w = f2bf((x.w - mean) * rstd * g4.w + b4.w);
  ((ushort4*)(out + (size_t)row * E_DIM))[tid] = o;
}

// ---------------- GEMM: C[M,N] = A[M,K] * Bw[N,K]^T (bf16 in, fp32 acc) ----
template <int MODE>
__global__ __launch_bounds__(256) void gemm_bt_kernel(
    const unsigned short* __restrict__ A, const unsigned short* __restrict__ Bw,
    const float* __restrict__ resid, unsigned short* __restrict__ out_qkv,
    float* __restrict__ out_f, int Kv, int Nv) {
  __shared__ alignas(16) unsigned short lA[128 * 32];
  __shared__ alignas(16) unsigned short lB[128 * 32];
  int tid = threadIdx.x;
  int wid = tid >> 6, lane = tid & 63;
  int wm = wid >> 1, wn = wid & 1;
  int g = lane >> 4, lr = lane & 15;
  int m0 = blockIdx.y * 128, n0 = blockIdx.x * 128;
  f32x4 acc[4][4] = {};

  for (int k0 = 0; k0 < Kv; k0 += 32) {
#pragma unroll
    for (int c = 0; c < 2; ++c) {
      int f16 = c * 256 + tid;
      int row = f16 >> 2, col8 = (f16 & 3) << 3;
      gload_lds16(A  + (size_t)(m0 + row) * Kv + k0 + col8,
                  lA + (size_t)(c * 256 + wid * 64) * 8);
      gload_lds16(Bw + (size_t)(n0 + row) * Kv + k0 + col8,
                  lB + (size_t)(c * 256 + wid * 64) * 8);
    }
    __syncthreads();
    bf16x8 af[4], bfr[4];
#pragma unroll
    for (int r = 0; r < 4; ++r) {
      af[r]  = *(const bf16x8*)(lA + (wm * 64 + r * 16 + lr) * 32 + g * 8);
      bfr[r] = *(const bf16x8*)(lB + (wn * 64 + r * 16 + lr) * 32 + g * 8);
    }
#pragma unroll
    for (int mr = 0; mr < 4; ++mr)
#pragma unroll
      for (int nr = 0; nr < 4; ++nr)
        acc[mr][nr] = __builtin_amdgcn_mfma_f32_16x16x32_bf16(
            af[mr], bfr[nr], acc[mr][nr], 0, 0, 0);
    __syncthreads();
  }

#pragma unroll
  for (int mr = 0; mr < 4; ++mr) {
#pragma unroll
    for (int nr = 0; nr < 4; ++nr) {
#pragma unroll
      for (int r = 0; r < 4; ++r) {
        int grow = m0 + wm * 64 + mr * 16 + g * 4 + r;
        int gcol = n0 + wn * 64 + nr * 16 + lr;
        float v = acc[mr][nr][r];
        if (MODE == 0) {
          int which = gcol >> 10, rem = gcol & 1023;
          int h = rem >> 6, d = rem & 63;
          int t = grow >> 1, b = grow & 1;
          out_qkv[(size_t)which * (BH_DIM * T_DIM * HD_DIM) +
                  ((size_t)(b * H_DIM + h) * T_DIM + t) * HD_DIM + d] = f2bf(v);
        } else {
          size_t idx = (size_t)grow * Nv + gcol;
          out_f[idx] = resid[idx] + v;
        }
      }
    }
  }
}

// ---------------- V transpose: [bh][t][d] -> [bh][d][pi(t)] ---------------
// Within each 64-t tile, output t-order is permuted by pi(t)=(t&15)*4+(t>>4)
// to match attn's packed-P k-ordering (contraction permutation-invariant).
__global__ __launch_bounds__(256) void transpose_v_kernel(
    const unsigned short* __restrict__ vb, unsigned short* __restrict__ vt) {
  __shared__ alignas(16) unsigned short tl[64 * 72];
  int tid = threadIdx.x;
  int bh = blockIdx.y, t0 = blockIdx.x * 64;
  const unsigned short* src = vb + ((size_t)bh * T_DIM + t0) * HD_DIM;
#pragma unroll
  for (int e = 0; e < 2; ++e) {
    int i8 = e * 256 + tid;
    int r = i8 >> 3;                  // t-row 0..63
    int c = (i8 & 7) * 8;             // d chunk
    int hsh = (r ^ (r >> 3)) & 7;
    bf16x8 v = *(const bf16x8*)(src + (size_t)r * HD_DIM + c);
    *(bf16x8*)(tl + r * 72 + (c ^ (hsh << 3))) = v;
  }
  __syncthreads();
  unsigned short* dst = vt + (size_t)bh * HD_DIM * T_DIM + t0;
#pragma unroll
  for (int e = 0; e < 2; ++e) {
    int i8 = e * 256 + tid;
    int d = i8 >> 3;                  // d-row 0..63
    int tc = (i8 & 7) * 8;            // phys t chunk
    u16x8 o;
#pragma unroll
    for (int j = 0; j < 8; ++j) {
      int p = tc + j;                           // phys position
      int r = ((p & 3) << 4) | (p >> 2);        // logical t = pi^-1(p)
      int hsh = (r ^ (r >> 3)) & 7;
      o[j] = tl[r * 72 + (d ^ (hsh << 3))];
    }
    *(u16x8*)(dst + (size_t)d * T_DIM + tc) = o;
  }
}

// ---------------- Flash attention (fixed-max softmax, MFMA row-sum) -------
// Per wave: 32 q-rows. Block: 128 q-rows, 4 waves. KV tile 64, 3-buffer
// rotation with ONE barrier per tile (buffer staged at t was last read at
// t-2; barrier(t-1) separates). P stored packed: lane's 4 cf-values land at
// phys cols lr*4+cf (pi(k)); V's t-columns pre-permuted identically.
__global__ __launch_bounds__(256) void attn_kernel(
    const unsigned short* __restrict__ qb, const unsigned short* __restrict__ kb,
    const unsigned short* __restrict__ vt, unsigned short* __restrict__ ctx) {
  __shared__ alignas(16) unsigned short lK[3][64 * 64];
  __shared__ alignas(16) unsigned short lV[3][64 * 64];
  __shared__ alignas(16) unsigned short lP[4][32 * 72];
  int tid = threadIdx.x;
  int wid = tid >> 6, lane = tid & 63;
  int g = lane >> 4, lr = lane & 15;
  int bh = blockIdx.y;
  int b = bh >> 4, h = bh & 15;
  int qt = blockIdx.x;
  const size_t koff = (size_t)bh * T_DIM * HD_DIM;   // q,k layout [bh][t][64]
  const size_t voff = (size_t)bh * HD_DIM * T_DIM;   // v^T layout [bh][64][T]

  int srow = tid >> 3;
  int gch  = (tid & 7) ^ (srow & 7);
  const unsigned short* ks0 = kb + koff + (size_t)srow * HD_DIM + gch * 8;
  const unsigned short* vs0 = vt + voff + (size_t)srow * T_DIM + gch * 8;

#define STAGE_TILE(buf, kofs, vofs)                                            \
  do {                                                                         \
    gload_lds16(ks0 + (kofs),                 lK[buf] + wid * 512);            \
    gload_lds16(ks0 + (kofs) + 32 * HD_DIM,   lK[buf] + 2048 + wid * 512);     \
    gload_lds16(vs0 + (vofs),                 lV[buf] + wid * 512);            \
    gload_lds16(vs0 + (vofs) + (size_t)32 * T_DIM, lV[buf] + 2048 + wid * 512);\
  } while (0)

  // Q fragments (32 rows/wave), scale 1/8 * log2(e) folded in
  bf16x8 qf[2][2];
  {
    const float QS = 0.125f * 1.44269504f;
#pragma unroll
    for (int qa = 0; qa < 2; ++qa) {
      int qrow = qt * 128 + wid * 32 + qa * 16 + lr;
#pragma unroll
      for (int ks = 0; ks < 2; ++ks) {
        bf16x8 raw = *(const bf16x8*)(qb + koff + (size_t)qrow * HD_DIM + ks * 32 + g * 8);
#pragma unroll
        for (int j = 0; j < 8; ++j) qf[qa][ks][j] = (__bf16)((float)raw[j] * QS);
      }
    }
  }

  bf16x8 onesf;
#pragma unroll
  for (int j = 0; j < 8; ++j) onesf[j] = (__bf16)1.0f;

  f32x4 accO[2][4] = {};
  f32x4 accS[2] = {};

  const int NT = T_DIM / 64;  // 32
  STAGE_TILE(0, 0, 0);        // prologue: tile 0

#define PROCESS(BUF, NBUF, TT, LAST)                                           \
  do {                                                                         \
    if (!(LAST)) {                                                             \
      size_t s1 = (size_t)((TT) + 1) * 64;                                     \
      STAGE_TILE(NBUF, s1 * HD_DIM, s1);                                       \
      asm volatile("s_waitcnt vmcnt(4)" ::: "memory");                         \
    } else {                                                                   \
      asm volatile("s_waitcnt vmcnt(0)" ::: "memory");                         \
    }                                                                          \
    __builtin_amdgcn_s_barrier();                                              \
    __builtin_amdgcn_sched_barrier(0);                                         \
    const unsigned short* Kc = lK[BUF];                                        \
    const unsigned short* Vc = lV[BUF];                                        \
    f32x4 s4[2][4];                                                            \
    __builtin_amdgcn_s_setprio(1);                                             \
    _Pragma("unroll")                                                          \
    for (int cf = 0; cf < 4; ++cf) {                                           \
      int row = cf * 16 + lr;                                                  \
      int sw = (row & 7) << 3;                                                 \
      bf16x8 k0 = *(const bf16x8*)(Kc + row * 64 + ((g * 8) ^ sw));            \
      bf16x8 k1 = *(const bf16x8*)(Kc + row * 64 + ((32 + g * 8) ^ sw));       \
      _Pragma("unroll")                                                        \
      for (int qa = 0; qa < 2; ++qa) {                                         \
        f32x4 s = {-8.0f, -8.0f, -8.0f, -8.0f};                                \
        s = __builtin_amdgcn_mfma_f32_16x16x32_bf16(qf[qa][0], k0, s, 0, 0, 0);\
        s = __builtin_amdgcn_mfma_f32_16x16x32_bf16(qf[qa][1], k1, s, 0, 0, 0);\
        s4[qa][cf] = s;                                                        \
      }                                                                        \
    }                                                                          \
    __builtin_amdgcn_s_setprio(0);                                             \
    _Pragma("unroll")                                                          \
    for (int qa = 0; qa < 2; ++qa)                                             \
      _Pragma("unroll")                                                        \
      for (int r = 0; r < 4; ++r) {                                            \
        u16x4 pk;                                                              \
        _Pragma("unroll")                                                      \
        for (int cf = 0; cf < 4; ++cf)                                         \
          pk[cf] = __builtin_bit_cast(unsigned short,                          \
                     (__bf16)__builtin_amdgcn_exp2f(s4[qa][cf][r]));           \
        *(u16x4*)(&lP[wid][(qa * 16 + g * 4 + r) * 72 + lr * 4]) = pk;         \
      }                                                                        \
    __builtin_amdgcn_s_setprio(1);                                             \
    _Pragma("unroll")                                                          \
    for (int ks = 0; ks < 2; ++ks) {                                           \
      bf16x8 pf[2];                                                            \
      _Pragma("unroll")                                                        \
      for (int qa = 0; qa < 2; ++qa) {                                         \
        pf[qa] = *(const bf16x8*)(&lP[wid][(qa * 16 + lr) * 72 + ks * 32 + g * 8]); \
        accS[qa] = __builtin_amdgcn_mfma_f32_16x16x32_bf16(pf[qa], onesf, accS[qa], 0, 0, 0); \
      }                                                                        \
      _Pragma("unroll")                                                        \
      for (int df = 0; df < 4; ++df) {                                         \
        int row = df * 16 + lr;                                                \
        int sw = (row & 7) << 3;                                               \
        bf16x8 vf = *(const bf16x8*)(Vc + row * 64 + ((ks * 32 + g * 8) ^ sw));\
        _Pragma("unroll")                                                      \
        for (int qa = 0; qa < 2; ++qa)                                         \
          accO[qa][df] = __builtin_amdgcn_mfma_f32_16x16x32_bf16(pf[qa], vf, accO[qa][df], 0, 0, 0); \
      }                                                                        \
    }                                                                          \
    __builtin_amdgcn_s_setprio(0);                                             \
  } while (0)

  for (int t3 = 0; t3 < 30; t3 += 3) {
    PROCESS(0, 1, t3 + 0, false);
    PROCESS(1, 2, t3 + 1, false);
    PROCESS(2, 0, t3 + 2, false);
  }
  PROCESS(0, 1, 30, false);
  PROCESS(1, 2, 31, true);
#undef PROCESS
#undef STAGE_TILE

  // ctx[t*B+b][h*64+d] bf16
#pragma unroll
  for (int qa = 0; qa < 2; ++qa) {
    float invl[4];
#pragma unroll
    for (int r = 0; r < 4; ++r) invl[r] = 1.0f / accS[qa][r];
#pragma unroll
    for (int df = 0; df < 4; ++df) {
#pragma unroll
      for (int r = 0; r < 4; ++r) {
        int t = qt * 128 + wid * 32 + qa * 16 + g * 4 + r;
        int col = h * HD_DIM + df * 16 + lr;
        float o = accO[qa][df][r] * invl[r];
        ctx[((size_t)t * B_DIM + b) * E_DIM + col] = f2bf(o);
      }
    }
  }
}

// ---------------- launcher ----------------
extern "C" void kernel_launch(void* const* d_in, const int* in_sizes, int n_in,
                              void* d_out, int out_size, void* d_ws, size_t ws_size,
                              hipStream_t stream) {
  const float* query = (const float*)d_in[0];
  const float* gamma = (const float*)d_in[1];
  const float* beta  = (const float*)d_in[2];
  const float* w_in  = (const float*)d_in[3];
  const float* w_out = (const float*)d_in[4];
  float* out = (float*)d_out;

  unsigned short* ws    = (unsigned short*)d_ws;
  unsigned short* ln    = ws;                                 // 4096*1024 (8 MB)
  unsigned short* winb  = ln + (size_t)M_DIM * E_DIM;         // 3072*1024
  unsigned short* woutb = winb + (size_t)3 * E_DIM * E_DIM;   // 1024*1024
  unsigned short* qkv   = woutb + (size_t)E_DIM * E_DIM;      // 3*32*2048*64

  unsigned short* qbuf = qkv;
  unsigned short* kbuf = qkv + (size_t)BH_DIM * T_DIM * HD_DIM;
  unsigned short* vbuf = kbuf + (size_t)BH_DIM * T_DIM * HD_DIM;
  unsigned short* vtb  = ln;    // reuse: ln consumed by GEMM0 before transpose
  unsigned short* ctx  = vbuf;  // reuse: vbuf consumed by transpose before attn

  cast_bf16_kernel<<<dim3(3072), dim3(256), 0, stream>>>(w_in, winb, 3 * E_DIM * E_DIM / 4);
  cast_bf16_kernel<<<dim3(1024), dim3(256), 0, stream>>>(w_out, woutb, E_DIM * E_DIM / 4);
  ln_kernel<<<dim3(M_DIM), dim3(256), 0, stream>>>(query, gamma, beta, ln);
  gemm_bt_kernel<0><<<dim3(3 * E_DIM / 128, M_DIM / 128), dim3(256), 0, stream>>>(
      ln, winb, nullptr, qkv, nullptr, E_DIM, 3 * E_DIM);
  transpose_v_kernel<<<dim3(T_DIM / 64, BH_DIM), dim3(256), 0, stream>>>(vbuf, vtb);
  attn_kernel<<<dim3(T_DIM / 128, BH_DIM), dim3(256), 0, stream>>>(qbuf, kbuf, vtb, ctx);
  gemm_bt_kernel<1><<<dim3(E_DIM / 128, M_DIM / 128), dim3(256), 0, stream>>>(
      ctx, woutb, query, nullptr, out, E_DIM, E_DIM);
}